// Round 1
// baseline (473.705 us; speedup 1.0000x reference)
//
#include <hip/hip_runtime.h>

// Problem config (fixed by the reference's setup_inputs)
constexpr int B     = 8;      // batch
constexpr int L     = 1024;   // new tokens per seq
constexpr int BS    = 16;     // block size (tokens per cache block)
constexpr int MAXB  = 128;    // max blocks per seq (layer slice of block_tables)
constexpr int H     = 8;      // kv heads
constexpr int D     = 128;    // head dim
constexpr int TOTAL = 2048;   // total physical blocks (= free_blocks size)
constexpr int CACHE_ELEMS = TOTAL * H * BS * D;   // 33,554,432 floats per cache

// ---------------------------------------------------------------------------
// Kernel A: rebuild the block-allocation inverse map.
// inv[blk] = (b << 20) | slot   if physical block `blk` receives new tokens
//          = -1                 otherwise
// Mirrors the reference's cumsum tail-pop allocation exactly, computed from
// the live inputs (no hardcoded allocation results).
// ---------------------------------------------------------------------------
__global__ void build_inv_kernel(const int* __restrict__ input_len,
                                 const int* __restrict__ block_tables,
                                 const int* __restrict__ seq_lens,
                                 const int* __restrict__ free_blocks,
                                 int* __restrict__ inv) {
    const int tid = threadIdx.x;
    for (int i = tid; i < TOTAL; i += blockDim.x) inv[i] = -1;
    __syncthreads();

    // Every thread redundantly computes the tiny (B=8) allocation prefix sums.
    int old_nb[B], new_nb[B], start[B];
    int cum = 0;
    for (int b = 0; b < B; ++b) {
        const int sl = seq_lens[b];
        old_nb[b] = (sl + BS - 1) / BS;
        new_nb[b] = (sl + input_len[b] + BS - 1) / BS;
        cum += new_nb[b] - old_nb[b];
        start[b] = TOTAL - cum;              // num_free == TOTAL
    }

    // Slots that receive at least one new token: j in [seq_lens/BS, new_nb)
    for (int b = 0; b < B; ++b) {
        const int j0 = seq_lens[b] / BS;
        for (int j = j0 + tid; j < new_nb[b]; j += blockDim.x) {
            int blk;
            if (j >= old_nb[b]) {
                int fi = start[b] + (j - old_nb[b]);
                fi = min(max(fi, 0), TOTAL - 1);   // reference's clip
                blk = free_blocks[fi];
            } else {
                blk = block_tables[b * MAXB + j];  // existing partial block
            }
            inv[blk] = (b << 20) | j;
        }
    }
}

// ---------------------------------------------------------------------------
// Kernel B: one-pass gather producing the full [2, TOTAL, H, BS, D] output.
// Each thread emits one float4 (16 B). For blocks receiving new tokens, the
// source is key_states/value_states; otherwise the original cache.
// ---------------------------------------------------------------------------
__global__ __launch_bounds__(256) void gather_out_kernel(
        const float4* __restrict__ key_states,
        const float4* __restrict__ value_states,
        const float4* __restrict__ k_cache,
        const float4* __restrict__ v_cache,
        const int*    __restrict__ input_len,
        const int*    __restrict__ cu_seqlens,
        const int*    __restrict__ seq_lens,
        const int*    __restrict__ inv,
        float4*       __restrict__ out) {
    constexpr int C4   = CACHE_ELEMS / 4;   // float4 per cache: 8,388,608
    constexpr int PB4  = H * BS * D / 4;    // float4 per block: 4096
    constexpr int PH4  = BS * D / 4;        // float4 per head:  512
    constexpr int PO4  = D / 4;             // float4 per token:  32

    const int idx4 = blockIdx.x * blockDim.x + threadIdx.x;
    if (idx4 >= 2 * C4) return;

    const int c    = idx4 >= C4 ? 1 : 0;    // 0 = K, 1 = V
    const int rel4 = idx4 - c * C4;

    const int blk = rel4 / PB4;             // all pow2 -> shifts
    int r         = rel4 - blk * PB4;
    const int h   = r / PH4;  r -= h * PH4;
    const int off = r / PO4;
    const int d4  = r - off * PO4;

    const int m = inv[blk];
    float4 val;
    bool from_cache = true;
    if (m >= 0) {
        const int b   = m >> 20;
        const int j   = m & 0xFFFFF;
        const int pos = j * BS + off;
        const int sl  = seq_lens[b];
        if (pos >= sl && pos < sl + input_len[b]) {
            const int tok = cu_seqlens[b] + (pos - sl);
            const float4* __restrict__ src = c ? value_states : key_states;
            val = src[tok * (H * D / 4) + h * PO4 + d4];
            from_cache = false;
        }
    }
    if (from_cache) {
        const float4* __restrict__ cache = c ? v_cache : k_cache;
        val = cache[rel4];
    }
    out[idx4] = val;
}

extern "C" void kernel_launch(void* const* d_in, const int* in_sizes, int n_in,
                              void* d_out, int out_size, void* d_ws, size_t ws_size,
                              hipStream_t stream) {
    // setup_inputs order:
    // 0 layer_idx, 1 key_states, 2 value_states, 3 input_len, 4 cu_seqlens,
    // 5 k_cache, 6 v_cache, 7 block_tables, 8 seq_lens, 9 free_blocks
    const float* key_states   = (const float*)d_in[1];
    const float* value_states = (const float*)d_in[2];
    const int*   input_len    = (const int*)d_in[3];
    const int*   cu_seqlens   = (const int*)d_in[4];
    const float* k_cache      = (const float*)d_in[5];
    const float* v_cache      = (const float*)d_in[6];
    const int*   block_tables = (const int*)d_in[7];
    const int*   seq_lens     = (const int*)d_in[8];
    const int*   free_blocks  = (const int*)d_in[9];

    int* inv = (int*)d_ws;                  // TOTAL ints = 8 KiB of workspace

    build_inv_kernel<<<1, 256, 0, stream>>>(input_len, block_tables, seq_lens,
                                            free_blocks, inv);

    const int total4 = 2 * CACHE_ELEMS / 4; // 16,777,216 float4 stores
    const int blocks = (total4 + 255) / 256;
    gather_out_kernel<<<blocks, 256, 0, stream>>>(
        (const float4*)key_states, (const float4*)value_states,
        (const float4*)k_cache, (const float4*)v_cache,
        input_len, cu_seqlens, seq_lens, inv, (float4*)d_out);
}